// Round 1
// baseline (31739.151 us; speedup 1.0000x reference)
//
#include <hip/hip_runtime.h>

// MGU forward: B rows, tau steps, HID hidden units, INPUT=1.
// Thread-per-row; H/F/acc in registers (static unroll); weights in LDS
// transposed [k][j] -> broadcast ds_read_b128 (conflict-free).

constexpr int BATCH = 131072;
constexpr int TAU   = 20;
constexpr int HID   = 64;
constexpr int FAN   = 65;   // INPUT + HID
constexpr int NT    = 256;  // threads per block

__device__ __forceinline__ float fast_sigmoid(float a) {
    // 1/(1+e^-a); v_exp-based, ~1 ulp exp + ~22-bit rcp: fine vs 1.2e-3 tol
    return __builtin_amdgcn_rcpf(1.0f + __expf(-a));
}
__device__ __forceinline__ float fast_tanh(float a) {
    // tanh(a) = 1 - 2/(e^{2a}+1); saturates correctly at +/-inf
    return 1.0f - 2.0f * __builtin_amdgcn_rcpf(1.0f + __expf(2.0f * a));
}

__global__ __launch_bounds__(NT, 2) void mgu_fwd(
    const float* __restrict__ x,   // [B, TAU]
    const float* __restrict__ h0,  // [B, HID]
    const float* __restrict__ Wf,  // [HID, FAN]
    const float* __restrict__ bf,  // [HID]
    const float* __restrict__ Wc,  // [HID, FAN]
    const float* __restrict__ bc,  // [HID]
    const float* __restrict__ Wo,  // [1, HID]
    const float* __restrict__ bo,  // [1]
    float* __restrict__ out)       // [B, 1]
{
    // Transposed weights: sW*[k][j] = W*[j][k]. Row = 64 floats = 256B,
    // 16B-aligned for float4 (ds_read_b128 broadcast).
    __shared__ float sWf[FAN][HID];
    __shared__ float sWc[FAN][HID];
    __shared__ float sbf[HID];
    __shared__ float sbc[HID];
    __shared__ float sWo[HID];

    const int tid = threadIdx.x;
    for (int i = tid; i < FAN * HID; i += NT) {
        const int k = i >> 6;        // i / HID
        const int j = i & (HID - 1); // i % HID
        sWf[k][j] = Wf[j * FAN + k];
        sWc[k][j] = Wc[j * FAN + k];
    }
    if (tid < HID) {
        sbf[tid] = bf[tid];
        sbc[tid] = bc[tid];
        sWo[tid] = Wo[tid];
    }
    __syncthreads();

    const int r = blockIdx.x * NT + tid;

    // Load H row (16x float4, per-lane 256B row)
    float H[HID];
    const float4* h0v = reinterpret_cast<const float4*>(h0 + (size_t)r * HID);
    #pragma unroll
    for (int i = 0; i < HID / 4; ++i) {
        float4 v = h0v[i];
        H[4*i+0] = v.x; H[4*i+1] = v.y; H[4*i+2] = v.z; H[4*i+3] = v.w;
    }

    const float* xr = x + (size_t)r * TAU;

    #pragma unroll 1
    for (int t = 0; t < TAU; ++t) {
        const float xt = xr[t];

        // ---- gate F: acc[j] = bf[j] + Wf[j][0]*xt + sum_k Wf[j][k+1]*H[k]
        float acc[HID];
        #pragma unroll
        for (int j4 = 0; j4 < HID / 4; ++j4) {
            float4 w = *reinterpret_cast<const float4*>(&sWf[0][4*j4]);
            float4 b = *reinterpret_cast<const float4*>(&sbf[4*j4]);
            acc[4*j4+0] = fmaf(w.x, xt, b.x);
            acc[4*j4+1] = fmaf(w.y, xt, b.y);
            acc[4*j4+2] = fmaf(w.z, xt, b.z);
            acc[4*j4+3] = fmaf(w.w, xt, b.w);
        }
        #pragma unroll
        for (int k = 0; k < HID; ++k) {
            const float hk = H[k];
            #pragma unroll
            for (int j4 = 0; j4 < HID / 4; ++j4) {
                float4 w = *reinterpret_cast<const float4*>(&sWf[k+1][4*j4]);
                acc[4*j4+0] = fmaf(w.x, hk, acc[4*j4+0]);
                acc[4*j4+1] = fmaf(w.y, hk, acc[4*j4+1]);
                acc[4*j4+2] = fmaf(w.z, hk, acc[4*j4+2]);
                acc[4*j4+3] = fmaf(w.w, hk, acc[4*j4+3]);
            }
        }
        // F = sigmoid(acc), in place (acc now holds F)
        #pragma unroll
        for (int j = 0; j < HID; ++j) acc[j] = fast_sigmoid(acc[j]);

        // ---- gate C: acc2[j] = bc[j] + Wc[j][0]*xt + sum_k Wc[j][k+1]*(F[k]*H[k])
        // While consuming column k, also fold H[k] -> P[k] = H[k] - F[k]*H[k].
        float acc2[HID];
        #pragma unroll
        for (int j4 = 0; j4 < HID / 4; ++j4) {
            float4 w = *reinterpret_cast<const float4*>(&sWc[0][4*j4]);
            float4 b = *reinterpret_cast<const float4*>(&sbc[4*j4]);
            acc2[4*j4+0] = fmaf(w.x, xt, b.x);
            acc2[4*j4+1] = fmaf(w.y, xt, b.y);
            acc2[4*j4+2] = fmaf(w.z, xt, b.z);
            acc2[4*j4+3] = fmaf(w.w, xt, b.w);
        }
        #pragma unroll
        for (int k = 0; k < HID; ++k) {
            const float g = acc[k] * H[k];  // F[k]*H[k]
            H[k] -= g;                      // P[k] = (1-F[k])*H[k]
            #pragma unroll
            for (int j4 = 0; j4 < HID / 4; ++j4) {
                float4 w = *reinterpret_cast<const float4*>(&sWc[k+1][4*j4]);
                acc2[4*j4+0] = fmaf(w.x, g, acc2[4*j4+0]);
                acc2[4*j4+1] = fmaf(w.y, g, acc2[4*j4+1]);
                acc2[4*j4+2] = fmaf(w.z, g, acc2[4*j4+2]);
                acc2[4*j4+3] = fmaf(w.w, g, acc2[4*j4+3]);
            }
        }

        // ---- update: H[j] = P[j] + F[j] * tanh(acc2[j])
        #pragma unroll
        for (int j = 0; j < HID; ++j) {
            H[j] = fmaf(acc[j], fast_tanh(acc2[j]), H[j]);
        }
    }

    // ---- output: out[r] = bo + sum_j Wo[j]*H[j]
    float s = 0.0f;
    #pragma unroll
    for (int j4 = 0; j4 < HID / 4; ++j4) {
        float4 w = *reinterpret_cast<const float4*>(&sWo[4*j4]);
        s = fmaf(w.x, H[4*j4+0], s);
        s = fmaf(w.y, H[4*j4+1], s);
        s = fmaf(w.z, H[4*j4+2], s);
        s = fmaf(w.w, H[4*j4+3], s);
    }
    out[r] = s + bo[0];
}

extern "C" void kernel_launch(void* const* d_in, const int* in_sizes, int n_in,
                              void* d_out, int out_size, void* d_ws, size_t ws_size,
                              hipStream_t stream) {
    const float* x  = (const float*)d_in[0];
    const float* h0 = (const float*)d_in[1];
    const float* Wf = (const float*)d_in[2];
    const float* bf = (const float*)d_in[3];
    const float* Wc = (const float*)d_in[4];
    const float* bc = (const float*)d_in[5];
    const float* Wo = (const float*)d_in[6];
    const float* bo = (const float*)d_in[7];
    float* out = (float*)d_out;

    dim3 grid(BATCH / NT);
    dim3 block(NT);
    hipLaunchKernelGGL(mgu_fwd, grid, block, 0, stream,
                       x, h0, Wf, bf, Wc, bc, Wo, bo, out);
}

// Round 2
// 18031.190 us; speedup vs baseline: 1.7602x; 1.7602x over previous
//
#include <hip/hip_runtime.h>

// MGU forward, B=131072 rows, TAU=20 steps, HID=64, INPUT=1.
// 4 lanes per row: lane sub (=tid&3) owns hidden units [sub*16, sub*16+16).
// Per-thread registers: H[16], F[16], g[16], acc[16]  (~95 VGPR, no spill).
// Cross-lane H/g broadcast via DPP quad_perm (lane quads == row groups).
// Weights transposed in LDS [k][j]; ds_read_b128 with 16-way broadcast /
// 2-way bank aliasing (free).

constexpr int BATCH = 131072;
constexpr int TAU   = 20;
constexpr int HID   = 64;
constexpr int FAN   = 65;       // INPUT + HID
constexpr int NT    = 256;      // threads per block
constexpr int LPR   = 4;        // lanes per row
constexpr int SL    = HID / LPR; // 16 units per lane

__device__ __forceinline__ float fast_sigmoid(float a) {
    return __builtin_amdgcn_rcpf(1.0f + __expf(-a));
}
__device__ __forceinline__ float fast_tanh(float a) {
    // tanh(a) = 1 - 2/(e^{2a}+1); saturates correctly
    return 1.0f - 2.0f * __builtin_amdgcn_rcpf(1.0f + __expf(2.0f * a));
}

// Broadcast the value held by lane (quad_base + SRC) to all 4 lanes of the quad.
template<int SRC>
__device__ __forceinline__ float quad_bcast(float v) {
    int i = __builtin_bit_cast(int, v);
    i = __builtin_amdgcn_mov_dpp(i, SRC * 0x55, 0xF, 0xF, false); // quad_perm[SRC,SRC,SRC,SRC]
    return __builtin_bit_cast(float, i);
}

// acc[0..15] += sum_{kk=0..15} W[k0+kk][jb + 0..15] * bcast<SRC>(src16[kk])
// sWrow0 = &sW[k0][jb], row stride = HID floats.
template<int SRC>
__device__ __forceinline__ void mv_quarter(const float* __restrict__ sWrow0,
                                           const float* __restrict__ src16,
                                           float* __restrict__ acc)
{
    #pragma unroll
    for (int kk = 0; kk < SL; ++kk) {
        const float hk = quad_bcast<SRC>(src16[kk]);
        const float4* wr = reinterpret_cast<const float4*>(sWrow0 + kk * HID);
        const float4 w0 = wr[0];
        const float4 w1 = wr[1];
        const float4 w2 = wr[2];
        const float4 w3 = wr[3];
        acc[ 0] = fmaf(w0.x, hk, acc[ 0]);
        acc[ 1] = fmaf(w0.y, hk, acc[ 1]);
        acc[ 2] = fmaf(w0.z, hk, acc[ 2]);
        acc[ 3] = fmaf(w0.w, hk, acc[ 3]);
        acc[ 4] = fmaf(w1.x, hk, acc[ 4]);
        acc[ 5] = fmaf(w1.y, hk, acc[ 5]);
        acc[ 6] = fmaf(w1.z, hk, acc[ 6]);
        acc[ 7] = fmaf(w1.w, hk, acc[ 7]);
        acc[ 8] = fmaf(w2.x, hk, acc[ 8]);
        acc[ 9] = fmaf(w2.y, hk, acc[ 9]);
        acc[10] = fmaf(w2.z, hk, acc[10]);
        acc[11] = fmaf(w2.w, hk, acc[11]);
        acc[12] = fmaf(w3.x, hk, acc[12]);
        acc[13] = fmaf(w3.y, hk, acc[13]);
        acc[14] = fmaf(w3.z, hk, acc[14]);
        acc[15] = fmaf(w3.w, hk, acc[15]);
    }
}

__global__ __launch_bounds__(NT, 4) void mgu_fwd(
    const float* __restrict__ x,   // [B, TAU]
    const float* __restrict__ h0,  // [B, HID]
    const float* __restrict__ Wf,  // [HID, FAN]
    const float* __restrict__ bf,  // [HID]
    const float* __restrict__ Wc,  // [HID, FAN]
    const float* __restrict__ bc,  // [HID]
    const float* __restrict__ Wo,  // [1, HID]
    const float* __restrict__ bo,  // [1]
    float* __restrict__ out)       // [B, 1]
{
    // Transposed weights: sW*[k][j] = W*[j][k]; row = 256B, float4-aligned.
    __shared__ float sWf[FAN][HID];
    __shared__ float sWc[FAN][HID];
    __shared__ float sbf[HID];
    __shared__ float sbc[HID];
    __shared__ float sWo[HID];

    const int tid = threadIdx.x;
    for (int i = tid; i < FAN * HID; i += NT) {
        const int k = i >> 6;        // i / HID
        const int j = i & (HID - 1); // i % HID
        sWf[k][j] = Wf[j * FAN + k];
        sWc[k][j] = Wc[j * FAN + k];
    }
    if (tid < HID) {
        sbf[tid] = bf[tid];
        sbc[tid] = bc[tid];
        sWo[tid] = Wo[tid];
    }
    __syncthreads();

    const int gt  = blockIdx.x * NT + tid;
    const int r   = gt >> 2;       // row
    const int sub = tid & 3;       // slice owner within quad
    const int jb  = sub * SL;      // this lane's j-slice base

    // Load this lane's 16-float slice of h0 (wave-contiguous 4KB)
    float H[SL];
    {
        const float4* h0v = reinterpret_cast<const float4*>(h0 + (size_t)r * HID + jb);
        #pragma unroll
        for (int i = 0; i < SL / 4; ++i) {
            float4 v = h0v[i];
            H[4*i+0] = v.x; H[4*i+1] = v.y; H[4*i+2] = v.z; H[4*i+3] = v.w;
        }
    }

    const float* xr = x + (size_t)r * TAU;

    #pragma unroll 1
    for (int t = 0; t < TAU; ++t) {
        const float xt = xr[t];

        // ---- forget gate: acc = bf + Wf[:,0]*xt + Wf[:,1:]*H  (this lane's 16 outputs)
        float acc[SL];
        #pragma unroll
        for (int i = 0; i < SL / 4; ++i) {
            float4 w = *reinterpret_cast<const float4*>(&sWf[0][jb + 4*i]);
            float4 b = *reinterpret_cast<const float4*>(&sbf[jb + 4*i]);
            acc[4*i+0] = fmaf(w.x, xt, b.x);
            acc[4*i+1] = fmaf(w.y, xt, b.y);
            acc[4*i+2] = fmaf(w.z, xt, b.z);
            acc[4*i+3] = fmaf(w.w, xt, b.w);
        }
        mv_quarter<0>(&sWf[1 +  0][jb], H, acc);
        mv_quarter<1>(&sWf[1 + 16][jb], H, acc);
        mv_quarter<2>(&sWf[1 + 32][jb], H, acc);
        mv_quarter<3>(&sWf[1 + 48][jb], H, acc);

        // F = sigmoid(acc); g = F*H; H -> P = (1-F)*H
        float F[SL], g[SL];
        #pragma unroll
        for (int j = 0; j < SL; ++j) {
            F[j] = fast_sigmoid(acc[j]);
            g[j] = F[j] * H[j];
            H[j] -= g[j];
        }

        // ---- candidate gate: acc = bc + Wc[:,0]*xt + Wc[:,1:]*(F.*H)
        #pragma unroll
        for (int i = 0; i < SL / 4; ++i) {
            float4 w = *reinterpret_cast<const float4*>(&sWc[0][jb + 4*i]);
            float4 b = *reinterpret_cast<const float4*>(&sbc[jb + 4*i]);
            acc[4*i+0] = fmaf(w.x, xt, b.x);
            acc[4*i+1] = fmaf(w.y, xt, b.y);
            acc[4*i+2] = fmaf(w.z, xt, b.z);
            acc[4*i+3] = fmaf(w.w, xt, b.w);
        }
        mv_quarter<0>(&sWc[1 +  0][jb], g, acc);
        mv_quarter<1>(&sWc[1 + 16][jb], g, acc);
        mv_quarter<2>(&sWc[1 + 32][jb], g, acc);
        mv_quarter<3>(&sWc[1 + 48][jb], g, acc);

        // ---- update: H = P + F * tanh(acc)
        #pragma unroll
        for (int j = 0; j < SL; ++j) {
            H[j] = fmaf(F[j], fast_tanh(acc[j]), H[j]);
        }
    }

    // ---- output: out[r] = bo + Wo . H   (partial per lane, reduce over quad)
    float s = 0.0f;
    #pragma unroll
    for (int i = 0; i < SL / 4; ++i) {
        float4 w = *reinterpret_cast<const float4*>(&sWo[jb + 4*i]);
        s = fmaf(w.x, H[4*i+0], s);
        s = fmaf(w.y, H[4*i+1], s);
        s = fmaf(w.z, H[4*i+2], s);
        s = fmaf(w.w, H[4*i+3], s);
    }
    s += __shfl_xor(s, 1, LPR);
    s += __shfl_xor(s, 2, LPR);
    if (sub == 0) out[r] = s + bo[0];
}

extern "C" void kernel_launch(void* const* d_in, const int* in_sizes, int n_in,
                              void* d_out, int out_size, void* d_ws, size_t ws_size,
                              hipStream_t stream) {
    const float* x  = (const float*)d_in[0];
    const float* h0 = (const float*)d_in[1];
    const float* Wf = (const float*)d_in[2];
    const float* bf = (const float*)d_in[3];
    const float* Wc = (const float*)d_in[4];
    const float* bc = (const float*)d_in[5];
    const float* Wo = (const float*)d_in[6];
    const float* bo = (const float*)d_in[7];
    float* out = (float*)d_out;

    dim3 grid((BATCH * LPR) / NT);   // 2048 blocks, 64 rows per block
    dim3 block(NT);
    hipLaunchKernelGGL(mgu_fwd, grid, block, 0, stream,
                       x, h0, Wf, bf, Wc, bc, Wo, bo, out);
}

// Round 3
// 17774.742 us; speedup vs baseline: 1.7856x; 1.0144x over previous
//
#include <hip/hip_runtime.h>

// MGU forward, B=131072 rows, TAU=20 steps, HID=64, INPUT=1.
// 4 lanes per row: lane sub (=tid&3) owns hidden units [sub*16, sub*16+16).
// ALL per-thread state is ext_vector_type SSA values with literal-constant
// element indices (macro-expanded) -> guaranteed VGPRs, no alloca, no scratch.
// Cross-lane H/g broadcast via DPP quad_perm. Weights transposed in LDS,
// ds_read_b128 (2-way bank aliasing within quad = free per m136).

constexpr int BATCH = 131072;
constexpr int TAU   = 20;
constexpr int HID   = 64;
constexpr int FAN   = 65;   // INPUT + HID
constexpr int NT    = 256;  // threads per block
constexpr int LPR   = 4;    // lanes per row
constexpr int SL    = 16;   // hidden units per lane

typedef float vf4  __attribute__((ext_vector_type(4)));
typedef float vf16 __attribute__((ext_vector_type(16)));

#define REP16(M) M(0) M(1) M(2) M(3) M(4) M(5) M(6) M(7) \
                 M(8) M(9) M(10) M(11) M(12) M(13) M(14) M(15)

__device__ __forceinline__ float fast_sigmoid(float a) {
    return __builtin_amdgcn_rcpf(1.0f + __expf(-a));
}
__device__ __forceinline__ float fast_tanh(float a) {
    // tanh(a) = 1 - 2/(e^{2a}+1); saturates correctly at +/-inf
    return 1.0f - 2.0f * __builtin_amdgcn_rcpf(1.0f + __expf(2.0f * a));
}

// Broadcast lane (quad_base + SRC)'s value to all 4 lanes of the quad.
template<int SRC>
__device__ __forceinline__ float quad_bcast(float v) {
    int i = __builtin_bit_cast(int, v);
    i = __builtin_amdgcn_mov_dpp(i, SRC * 0x55, 0xF, 0xF, false); // quad_perm[S,S,S,S]
    return __builtin_bit_cast(float, i);
}

// acc[0..15] += sum_{kk=0..15} W[kk][0..15] * quad_bcast<SRC>(src[kk])
// w0p = &sW[k0][jb]; row stride HID floats. All element indices literal.
template<int SRC>
__device__ __forceinline__ vf16 mv_quarter(const float* __restrict__ w0p,
                                           vf16 src, vf16 acc)
{
#define ONE_K(kk) { \
    const float hk = quad_bcast<SRC>(src[kk]); \
    const vf4* wr = reinterpret_cast<const vf4*>(w0p + (kk) * HID); \
    const vf4 wa = wr[0], wb = wr[1], wc = wr[2], wd = wr[3]; \
    acc[0]  = fmaf(wa[0], hk, acc[0]);  acc[1]  = fmaf(wa[1], hk, acc[1]); \
    acc[2]  = fmaf(wa[2], hk, acc[2]);  acc[3]  = fmaf(wa[3], hk, acc[3]); \
    acc[4]  = fmaf(wb[0], hk, acc[4]);  acc[5]  = fmaf(wb[1], hk, acc[5]); \
    acc[6]  = fmaf(wb[2], hk, acc[6]);  acc[7]  = fmaf(wb[3], hk, acc[7]); \
    acc[8]  = fmaf(wc[0], hk, acc[8]);  acc[9]  = fmaf(wc[1], hk, acc[9]); \
    acc[10] = fmaf(wc[2], hk, acc[10]); acc[11] = fmaf(wc[3], hk, acc[11]); \
    acc[12] = fmaf(wd[0], hk, acc[12]); acc[13] = fmaf(wd[1], hk, acc[13]); \
    acc[14] = fmaf(wd[2], hk, acc[14]); acc[15] = fmaf(wd[3], hk, acc[15]); }
    REP16(ONE_K)
#undef ONE_K
    return acc;
}

// acc[j] = b[j] + w0[j]*xt for this lane's 16-j slice
__device__ __forceinline__ vf16 gate_init(const float* __restrict__ w0p,
                                          const float* __restrict__ bp, float xt)
{
    const vf4* w = reinterpret_cast<const vf4*>(w0p);
    const vf4* b = reinterpret_cast<const vf4*>(bp);
    const vf4 w0 = w[0], w1 = w[1], w2 = w[2], w3 = w[3];
    const vf4 b0 = b[0], b1 = b[1], b2 = b[2], b3 = b[3];
    vf16 acc;
    acc[0]  = fmaf(w0[0], xt, b0[0]);  acc[1]  = fmaf(w0[1], xt, b0[1]);
    acc[2]  = fmaf(w0[2], xt, b0[2]);  acc[3]  = fmaf(w0[3], xt, b0[3]);
    acc[4]  = fmaf(w1[0], xt, b1[0]);  acc[5]  = fmaf(w1[1], xt, b1[1]);
    acc[6]  = fmaf(w1[2], xt, b1[2]);  acc[7]  = fmaf(w1[3], xt, b1[3]);
    acc[8]  = fmaf(w2[0], xt, b2[0]);  acc[9]  = fmaf(w2[1], xt, b2[1]);
    acc[10] = fmaf(w2[2], xt, b2[2]);  acc[11] = fmaf(w2[3], xt, b2[3]);
    acc[12] = fmaf(w3[0], xt, b3[0]);  acc[13] = fmaf(w3[1], xt, b3[1]);
    acc[14] = fmaf(w3[2], xt, b3[2]);  acc[15] = fmaf(w3[3], xt, b3[3]);
    return acc;
}

__global__ __launch_bounds__(NT, 4) void mgu_fwd(
    const float* __restrict__ x,   // [B, TAU]
    const float* __restrict__ h0,  // [B, HID]
    const float* __restrict__ Wf,  // [HID, FAN]
    const float* __restrict__ bf,  // [HID]
    const float* __restrict__ Wc,  // [HID, FAN]
    const float* __restrict__ bc,  // [HID]
    const float* __restrict__ Wo,  // [1, HID]
    const float* __restrict__ bo,  // [1]
    float* __restrict__ out)       // [B, 1]
{
    // Transposed weights: sW*[k][j] = W*[j][k]; row = 256B, 16B-aligned.
    __shared__ float sWf[FAN][HID];
    __shared__ float sWc[FAN][HID];
    __shared__ float sbf[HID];
    __shared__ float sbc[HID];
    __shared__ float sWo[HID];

    const int tid = threadIdx.x;
    for (int i = tid; i < FAN * HID; i += NT) {
        const int k = i >> 6;        // i / HID
        const int j = i & (HID - 1); // i % HID
        sWf[k][j] = Wf[j * FAN + k];
        sWc[k][j] = Wc[j * FAN + k];
    }
    if (tid < HID) {
        sbf[tid] = bf[tid];
        sbc[tid] = bc[tid];
        sWo[tid] = Wo[tid];
    }
    __syncthreads();

    const int gt  = blockIdx.x * NT + tid;
    const int r   = gt >> 2;       // row
    const int sub = tid & 3;       // slice owner within quad
    const int jb  = sub * SL;      // this lane's j-slice base

    // This lane's 16-float slice of h0 (wave reads 16 rows x 256B contiguous)
    vf16 H = *reinterpret_cast<const vf16*>(h0 + (size_t)r * HID + jb);

    const float* xr = x + (size_t)r * TAU;
    float xt = xr[0];

    #pragma unroll 1
    for (int t = 0; t < TAU; ++t) {
        const float xn = (t + 1 < TAU) ? xr[t + 1] : 0.0f;  // prefetch next x

        // ---- forget gate
        vf16 acc = gate_init(&sWf[0][jb], &sbf[jb], xt);
        acc = mv_quarter<0>(&sWf[1 +  0][jb], H, acc);
        acc = mv_quarter<1>(&sWf[1 + 16][jb], H, acc);
        acc = mv_quarter<2>(&sWf[1 + 32][jb], H, acc);
        acc = mv_quarter<3>(&sWf[1 + 48][jb], H, acc);

        vf16 F;
#define SIG(j) F[j] = fast_sigmoid(acc[j]);
        REP16(SIG)
#undef SIG

        const vf16 g = F * H;   // forget-gated state (candidate input)

        // ---- candidate gate
        acc = gate_init(&sWc[0][jb], &sbc[jb], xt);
        acc = mv_quarter<0>(&sWc[1 +  0][jb], g, acc);
        acc = mv_quarter<1>(&sWc[1 + 16][jb], g, acc);
        acc = mv_quarter<2>(&sWc[1 + 32][jb], g, acc);
        acc = mv_quarter<3>(&sWc[1 + 48][jb], g, acc);

        // ---- update: H = H + F*(tanh(acc) - H)  == (1-F)H + F*tanh
#define UPD(j) H[j] = fmaf(F[j], fast_tanh(acc[j]) - H[j], H[j]);
        REP16(UPD)
#undef UPD

        xt = xn;
    }

    // ---- output: out[r] = bo + Wo . H  (partial per lane, reduce over quad)
    const vf4* wop = reinterpret_cast<const vf4*>(&sWo[jb]);
    const vf4 w0 = wop[0], w1 = wop[1], w2 = wop[2], w3 = wop[3];
    float s = 0.0f;
    s = fmaf(w0[0], H[0],  s); s = fmaf(w0[1], H[1],  s);
    s = fmaf(w0[2], H[2],  s); s = fmaf(w0[3], H[3],  s);
    s = fmaf(w1[0], H[4],  s); s = fmaf(w1[1], H[5],  s);
    s = fmaf(w1[2], H[6],  s); s = fmaf(w1[3], H[7],  s);
    s = fmaf(w2[0], H[8],  s); s = fmaf(w2[1], H[9],  s);
    s = fmaf(w2[2], H[10], s); s = fmaf(w2[3], H[11], s);
    s = fmaf(w3[0], H[12], s); s = fmaf(w3[1], H[13], s);
    s = fmaf(w3[2], H[14], s); s = fmaf(w3[3], H[15], s);

    s += __shfl_xor(s, 1, LPR);
    s += __shfl_xor(s, 2, LPR);
    if (sub == 0) out[r] = s + bo[0];
}

extern "C" void kernel_launch(void* const* d_in, const int* in_sizes, int n_in,
                              void* d_out, int out_size, void* d_ws, size_t ws_size,
                              hipStream_t stream) {
    const float* x  = (const float*)d_in[0];
    const float* h0 = (const float*)d_in[1];
    const float* Wf = (const float*)d_in[2];
    const float* bf = (const float*)d_in[3];
    const float* Wc = (const float*)d_in[4];
    const float* bc = (const float*)d_in[5];
    const float* Wo = (const float*)d_in[6];
    const float* bo = (const float*)d_in[7];
    float* out = (float*)d_out;

    dim3 grid((BATCH * LPR) / NT);   // 2048 blocks, 64 rows per block
    dim3 block(NT);
    hipLaunchKernelGGL(mgu_fwd, grid, block, 0, stream,
                       x, h0, Wf, bf, Wc, bc, Wo, bo, out);
}